// Round 1
// baseline (1464.538 us; speedup 1.0000x reference)
//
#include <hip/hip_runtime.h>

#define NB 32
#define NQ 1024
#define NKV 1024
#define DH 512
#define BQ 32     // Q rows per block
#define KT 64     // K-chunk
#define NTHR 512  // 8 waves
#define MASKV -1000000.0f

typedef unsigned short u16;
typedef __attribute__((ext_vector_type(4))) float f32x4;
typedef __attribute__((ext_vector_type(8))) short bf8;

__device__ __forceinline__ u16 f2bf(float x) {
  unsigned u = __float_as_uint(x);
  u += 0x7fffu + ((u >> 16) & 1u);   // RNE
  return (u16)(u >> 16);
}
__device__ __forceinline__ float bf2f(u16 h) {
  return __uint_as_float(((unsigned)h) << 16);
}
// element-level XOR swizzle: spreads 16 same-column rows over 8 16B slots (G4)
__device__ __forceinline__ int swz(int row, int col) {
  return col ^ ((row & 7) << 3);
}

__global__ void prep_w_kernel(const float* __restrict__ W, u16* __restrict__ whi,
                              u16* __restrict__ wlo) {
  int i = (blockIdx.x * 256 + threadIdx.x) * 4;
  float4 f = *reinterpret_cast<const float4*>(W + i);
  const float* fp = (const float*)&f;
#pragma unroll
  for (int j = 0; j < 4; ++j) {
    float x = fp[j];
    u16 h = f2bf(x);
    whi[i + j] = h;
    wlo[i + j] = f2bf(x - bf2f(h));
  }
}

__global__ __launch_bounds__(NTHR)
void attn_kernel(const float* __restrict__ Qg, const float* __restrict__ Kg,
                 const float* __restrict__ Vg, const float* __restrict__ Lg,
                 const int* __restrict__ vlraw, const u16* __restrict__ Whi,
                 const u16* __restrict__ Wlo, float* __restrict__ Og) {
  __shared__ u16 sPhi[BQ * DH];     // proj hi  (32 KB)
  __shared__ u16 sPlo[BQ * DH];     // proj lo  (32 KB)
  __shared__ u16 sSthi[16384];      // stage hi (32 KB): Q[32][512] / Kc[64][256] / Vt[256][64]
  __shared__ u16 sStlo[16384];      // stage lo (32 KB)
  __shared__ u16 sAhi[BQ * KT];     // attn tile hi (4 KB)
  __shared__ u16 sAlo[BQ * KT];
  __shared__ float sM[BQ], sL[BQ], sScale[BQ];
  __shared__ float sPmax[4][BQ], sPsum[4][BQ];

  int bid = blockIdx.x;
  int swb = (bid & 7) * 128 + (bid >> 3);  // XCD-aware swizzle (1024 % 8 == 0, bijective)
  int b = swb >> 5, qt = swb & 31;
  int tid = threadIdx.x;
  int wid = tid >> 6, lane = tid & 63;
  int l15 = lane & 15, l16 = lane >> 4;

  // valid_lens may be int64 (reference) or int32 (harness cast); detect:
  bool is64 = true;
  for (int j = 1; j < 32; j += 2) is64 = is64 && (vlraw[j] == 0);
  int vl = is64 ? vlraw[2 * b] : vlraw[b];
  bool allm = (vl == 0);            // all-masked => uniform softmax
  int vleff = allm ? NKV : vl;
  int nch = (vleff + KT - 1) / KT;  // skip fully-masked chunks

  if (tid < BQ) { sM[tid] = -1e30f; sL[tid] = 0.0f; }

  // ---- Phase 1a: stage Q tile fp32 -> hi/lo bf16 into stage buffer [32][512]
  {
    int row = tid >> 4;
    int dg = (tid & 15) * 32;
    const float4* src = reinterpret_cast<const float4*>(
        Qg + ((size_t)(b * NQ + qt * BQ + row)) * DH + dg);
    float4 f[8];
#pragma unroll
    for (int i = 0; i < 8; ++i) f[i] = src[i];
    const float* fp = (const float*)&f[0];
#pragma unroll
    for (int g = 0; g < 4; ++g) {
      bf8 vh, vlo2;
#pragma unroll
      for (int j = 0; j < 8; ++j) {
        float x = fp[g * 8 + j];
        u16 h = f2bf(x);
        vh[j] = (short)h;
        vlo2[j] = (short)f2bf(x - bf2f(h));
      }
      int idx = row * DH + swz(row, dg + g * 8);
      *(bf8*)(&sSthi[idx]) = vh;
      *(bf8*)(&sStlo[idx]) = vlo2;
    }
  }
  __syncthreads();

  // ---- Phase 1b: P = Q @ W^T (split bf16, 3 terms). Wave owns cols [wid*64, wid*64+64)
  f32x4 zero4 = {0.f, 0.f, 0.f, 0.f};
  f32x4 accP[2][4];
#pragma unroll
  for (int mi = 0; mi < 2; ++mi)
#pragma unroll
    for (int es = 0; es < 4; ++es) accP[mi][es] = zero4;

  for (int kk = 0; kk < DH; kk += 32) {
    bf8 qh[2], ql[2];
#pragma unroll
    for (int mi = 0; mi < 2; ++mi) {
      int row = mi * 16 + l15;
      int idx = row * DH + swz(row, kk + l16 * 8);
      qh[mi] = *(const bf8*)(&sSthi[idx]);
      ql[mi] = *(const bf8*)(&sStlo[idx]);
    }
#pragma unroll
    for (int es = 0; es < 4; ++es) {
      int e = wid * 64 + es * 16 + l15;
      int off = e * DH + kk + l16 * 8;
      bf8 wh = *(const bf8*)(Whi + off);
      bf8 wl = *(const bf8*)(Wlo + off);
#pragma unroll
      for (int mi = 0; mi < 2; ++mi) {
        accP[mi][es] = __builtin_amdgcn_mfma_f32_16x16x32_bf16(qh[mi], wh, accP[mi][es], 0, 0, 0);
        accP[mi][es] = __builtin_amdgcn_mfma_f32_16x16x32_bf16(qh[mi], wl, accP[mi][es], 0, 0, 0);
        accP[mi][es] = __builtin_amdgcn_mfma_f32_16x16x32_bf16(ql[mi], wh, accP[mi][es], 0, 0, 0);
      }
    }
  }
  // write P (hi/lo) to LDS; C/D layout: col=lane&15, row=(lane>>4)*4+r
#pragma unroll
  for (int mi = 0; mi < 2; ++mi)
#pragma unroll
    for (int es = 0; es < 4; ++es)
#pragma unroll
      for (int r = 0; r < 4; ++r) {
        int row = mi * 16 + l16 * 4 + r;
        int col = wid * 64 + es * 16 + l15;
        float x = accP[mi][es][r];
        u16 h = f2bf(x);
        int idx = row * DH + swz(row, col);
        sPhi[idx] = h;
        sPlo[idx] = f2bf(x - bf2f(h));
      }
  __syncthreads();

  // ---- Phase 2/3: flash loop over K-chunks
  int mq = wid >> 2, nk = wid & 3;  // S-subtile: rows mq*16.., cols nk*16..
  f32x4 accV[8], accL[8];
#pragma unroll
  for (int i = 0; i < 8; ++i) { accV[i] = zero4; accL[i] = zero4; }

  const float rscale = 0.04419417382415922f;  // 1/sqrt(512)

  for (int kc = 0; kc < nch; ++kc) {
    int kbase = kc * KT;
    // --- S = P @ Kc^T over 2 d-slices of 256
    f32x4 accS = zero4;
#pragma unroll
    for (int dsl = 0; dsl < DH; dsl += 256) {
      __syncthreads();  // stage buffer free
      {
        int row = tid >> 3;          // 0..63
        int dg = (tid & 7) * 32;
        const float4* src = reinterpret_cast<const float4*>(
            Kg + ((size_t)(b * NKV + kbase + row)) * DH + dsl + dg);
        float4 f[8];
#pragma unroll
        for (int i = 0; i < 8; ++i) f[i] = src[i];
        const float* fp = (const float*)&f[0];
#pragma unroll
        for (int g = 0; g < 4; ++g) {
          bf8 vh, vlo2;
#pragma unroll
          for (int j = 0; j < 8; ++j) {
            float x = fp[g * 8 + j];
            u16 h = f2bf(x);
            vh[j] = (short)h;
            vlo2[j] = (short)f2bf(x - bf2f(h));
          }
          int idx = row * 256 + swz(row, dg + g * 8);
          *(bf8*)(&sSthi[idx]) = vh;
          *(bf8*)(&sStlo[idx]) = vlo2;
        }
      }
      __syncthreads();
#pragma unroll
      for (int kk = 0; kk < 256; kk += 32) {
        int arow = mq * 16 + l15;
        int aidx = arow * DH + swz(arow, dsl + kk + l16 * 8);
        bf8 ah = *(const bf8*)(&sPhi[aidx]);
        bf8 al = *(const bf8*)(&sPlo[aidx]);
        int brow = nk * 16 + l15;
        int bidx = brow * 256 + swz(brow, kk + l16 * 8);
        bf8 bh = *(const bf8*)(&sSthi[bidx]);
        bf8 bl = *(const bf8*)(&sStlo[bidx]);
        accS = __builtin_amdgcn_mfma_f32_16x16x32_bf16(ah, bh, accS, 0, 0, 0);
        accS = __builtin_amdgcn_mfma_f32_16x16x32_bf16(ah, bl, accS, 0, 0, 0);
        accS = __builtin_amdgcn_mfma_f32_16x16x32_bf16(al, bh, accS, 0, 0, 0);
      }
    }

    // --- online softmax on wave's 16x16 subtile
    int colg = kbase + nk * 16 + l15;
    float s[4], mx[4];
#pragma unroll
    for (int r = 0; r < 4; ++r) {
      float x = accS[r] * rscale;
      s[r] = allm ? 0.0f : (colg < vl ? x : MASKV);
      mx[r] = s[r];
    }
#pragma unroll
    for (int off = 1; off < 16; off <<= 1)
#pragma unroll
      for (int r = 0; r < 4; ++r) mx[r] = fmaxf(mx[r], __shfl_xor(mx[r], off));
    if (l15 == 0)
#pragma unroll
      for (int r = 0; r < 4; ++r) sPmax[nk][mq * 16 + l16 * 4 + r] = mx[r];
    __syncthreads();

    float p[4], ps[4];
#pragma unroll
    for (int r = 0; r < 4; ++r) {
      int row = mq * 16 + l16 * 4 + r;
      float mc = fmaxf(fmaxf(sPmax[0][row], sPmax[1][row]),
                       fmaxf(sPmax[2][row], sPmax[3][row]));
      float mn = fmaxf(sM[row], mc);
      p[r] = __expf(s[r] - mn);
      ps[r] = p[r];
    }
#pragma unroll
    for (int off = 1; off < 16; off <<= 1)
#pragma unroll
      for (int r = 0; r < 4; ++r) ps[r] += __shfl_xor(ps[r], off);
    if (l15 == 0)
#pragma unroll
      for (int r = 0; r < 4; ++r) sPsum[nk][mq * 16 + l16 * 4 + r] = ps[r];
    // write attention tile (hi/lo)
#pragma unroll
    for (int r = 0; r < 4; ++r) {
      int row = mq * 16 + l16 * 4 + r;
      int col = nk * 16 + l15;
      u16 h = f2bf(p[r]);
      int idx = row * KT + swz(row, col);
      sAhi[idx] = h;
      sAlo[idx] = f2bf(p[r] - bf2f(h));
    }
    __syncthreads();

    if (nk == 0 && l15 == 0) {  // single writer per row
#pragma unroll
      for (int r = 0; r < 4; ++r) {
        int row = mq * 16 + l16 * 4 + r;
        float mc = fmaxf(fmaxf(sPmax[0][row], sPmax[1][row]),
                         fmaxf(sPmax[2][row], sPmax[3][row]));
        float mn = fmaxf(sM[row], mc);
        float sc = __expf(sM[row] - mn);
        sScale[row] = sc;
        sL[row] = sL[row] * sc + (sPsum[0][row] + sPsum[1][row] + sPsum[2][row] + sPsum[3][row]);
        sM[row] = mn;
      }
    }
    __syncthreads();

    // rescale accumulators
    float sc4[4];
#pragma unroll
    for (int r = 0; r < 4; ++r) sc4[r] = sScale[mq * 16 + l16 * 4 + r];
#pragma unroll
    for (int i = 0; i < 8; ++i)
#pragma unroll
      for (int r = 0; r < 4; ++r) { accV[i][r] *= sc4[r]; accL[i][r] *= sc4[r]; }

    // --- OV += A @ Vc ; OL += A @ Lc  (Vt staged transposed [256][64])
#pragma unroll
    for (int mat = 0; mat < 2; ++mat) {
      const float* src0 = (mat == 0) ? Vg : Lg;
#pragma unroll
      for (int dsl = 0; dsl < DH; dsl += 256) {
        __syncthreads();
        {
          int n = tid & 63;
          int dg = (tid >> 6) * 32;
          const float4* s4 = reinterpret_cast<const float4*>(
              src0 + ((size_t)(b * NKV + kbase + n)) * DH + dsl + dg);
          float4 f[8];
#pragma unroll
          for (int i = 0; i < 8; ++i) f[i] = s4[i];
          const float* fp = (const float*)&f[0];
#pragma unroll
          for (int j = 0; j < 32; ++j) {
            float x = fp[j];
            u16 h = f2bf(x);
            int d = dg + j;
            int idx = d * 64 + swz(d, n);
            sSthi[idx] = h;
            sStlo[idx] = f2bf(x - bf2f(h));
          }
        }
        __syncthreads();
        bf8 ah[2], al[2];
#pragma unroll
        for (int ks = 0; ks < 2; ++ks) {
          int arow = mq * 16 + l15;
          int aidx = arow * KT + swz(arow, ks * 32 + l16 * 8);
          ah[ks] = *(const bf8*)(&sAhi[aidx]);
          al[ks] = *(const bf8*)(&sAlo[aidx]);
        }
#pragma unroll
        for (int d4 = 0; d4 < 4; ++d4) {
          int dsub = (wid & 3) + d4 * 4;
          int ai = (dsl >> 8) * 4 + d4;
          f32x4 acc = (mat == 0) ? accV[ai] : accL[ai];
#pragma unroll
          for (int ks = 0; ks < 2; ++ks) {
            int brow = dsub * 16 + l15;
            int bidx = brow * 64 + swz(brow, ks * 32 + l16 * 8);
            bf8 bh = *(const bf8*)(&sSthi[bidx]);
            bf8 bl = *(const bf8*)(&sStlo[bidx]);
            acc = __builtin_amdgcn_mfma_f32_16x16x32_bf16(ah[ks], bh, acc, 0, 0, 0);
            acc = __builtin_amdgcn_mfma_f32_16x16x32_bf16(ah[ks], bl, acc, 0, 0, 0);
            acc = __builtin_amdgcn_mfma_f32_16x16x32_bf16(al[ks], bh, acc, 0, 0, 0);
          }
          if (mat == 0) accV[ai] = acc; else accL[ai] = acc;
        }
      }
    }
  }

  // ---- epilogue: divide by l, store
  float linv[4];
#pragma unroll
  for (int r = 0; r < 4; ++r) linv[r] = 1.0f / sL[mq * 16 + l16 * 4 + r];
  float* outV = Og;
  float* outL = Og + (size_t)NB * NQ * DH;
#pragma unroll
  for (int sl = 0; sl < 2; ++sl)
#pragma unroll
    for (int d4 = 0; d4 < 4; ++d4) {
      int ai = sl * 4 + d4;
      int d = sl * 256 + ((wid & 3) + d4 * 4) * 16 + l15;
#pragma unroll
      for (int r = 0; r < 4; ++r) {
        int q = qt * BQ + mq * 16 + l16 * 4 + r;
        size_t off = ((size_t)(b * NQ + q)) * DH + d;
        outV[off] = accV[ai][r] * linv[r];
        outL[off] = accL[ai][r] * linv[r];
      }
    }
}

extern "C" void kernel_launch(void* const* d_in, const int* in_sizes, int n_in,
                              void* d_out, int out_size, void* d_ws, size_t ws_size,
                              hipStream_t stream) {
  (void)in_sizes; (void)n_in; (void)out_size; (void)ws_size;
  const float* Qg = (const float*)d_in[0];
  const float* Kg = (const float*)d_in[1];
  const float* Vg = (const float*)d_in[2];
  const float* Lg = (const float*)d_in[3];
  const float* W  = (const float*)d_in[4];
  const int* vl   = (const int*)d_in[5];
  float* Og = (float*)d_out;
  u16* whi = (u16*)d_ws;            // 512 KB
  u16* wlo = whi + 512 * 512;       // 512 KB  (ws needs 1 MB)
  prep_w_kernel<<<dim3(256), dim3(256), 0, stream>>>(W, whi, wlo);
  attn_kernel<<<dim3(1024), dim3(NTHR), 0, stream>>>(Qg, Kg, Vg, Lg, vl, whi, wlo, Og);
}

// Round 2
// 1238.312 us; speedup vs baseline: 1.1827x; 1.1827x over previous
//
#include <hip/hip_runtime.h>

#define NB 32
#define NQ 1024
#define NKV 1024
#define DH 512
#define BQ 32     // Q rows per block
#define KT 64     // K-chunk
#define NTHR 512  // 8 waves
#define MASKV -1000000.0f

typedef unsigned short u16;
typedef __attribute__((ext_vector_type(4))) float f32x4;
typedef __attribute__((ext_vector_type(8))) short bf8;

__device__ __forceinline__ u16 f2bf(float x) {
  unsigned u = __float_as_uint(x);
  u += 0x7fffu + ((u >> 16) & 1u);   // RNE
  return (u16)(u >> 16);
}
__device__ __forceinline__ float bf2f(u16 h) {
  return __uint_as_float(((unsigned)h) << 16);
}
__device__ __forceinline__ int swz(int row, int col) {
  return col ^ ((row & 7) << 3);
}

// ---------------- workspace layout (fast path) ----------------
#define O_VLI   0u                      // 64 ints: vl[32], nch[32]
#define O_WTHI  1024u                   // Wt hi: [512 d][512 e] bf16
#define O_WTLO  (O_WTHI + 524288u)
#define O_KFHI  (O_WTLO + 524288u)      // K' frag-major hi (32 MB)
#define O_KFLO  (O_KFHI + 33554432u)
#define O_VTHI  (O_KFLO + 33554432u)
#define O_VTLO  (O_VTHI + 33554432u)
#define O_LTHI  (O_VTLO + 33554432u)
#define O_LTLO  (O_LTHI + 33554432u)
#define WS_NEED (size_t)(O_LTLO + 33554432u)

// ---------------- fast-path prologue kernels ----------------

// Wt[d][e] = W[e][d] as hi/lo bf16; also decode valid_lens
__global__ void prep_fast(const float* __restrict__ W, const int* __restrict__ vlraw,
                          u16* __restrict__ wthi, u16* __restrict__ wtlo,
                          int* __restrict__ vli) {
  int i = blockIdx.x * 256 + threadIdx.x;  // 0..262143 ; i = d*512 + e
  int d = i >> 9, e = i & 511;
  float x = W[e * 512 + d];
  u16 h = f2bf(x);
  wthi[i] = h;
  wtlo[i] = f2bf(x - bf2f(h));
  if (blockIdx.x == 0 && threadIdx.x < 32) {
    bool is64 = true;
    for (int j = 1; j < 32; j += 2) is64 = is64 && (vlraw[j] == 0);
    int vl = is64 ? vlraw[2 * threadIdx.x] : vlraw[threadIdx.x];
    int vleff = (vl == 0) ? NKV : vl;
    vli[threadIdx.x] = vl;
    vli[32 + threadIdx.x] = (vleff + KT - 1) / KT;  // nch
  }
}

// K' = K @ W  (3-term split bf16), emitted in fragment-major hi/lo layout:
// frag elem idx = ((t*16 + g)*64 + l16*16 + l15)*8 + j
//   t = global key-tile (16 keys), g = d/32, l16 = (d%32)/8, l15 = key%16, j = d%8
__global__ __launch_bounds__(512)
void projk(const float* __restrict__ Kg, const u16* __restrict__ wthi,
           const u16* __restrict__ wtlo, const int* __restrict__ vli,
           u16* __restrict__ kfhi, u16* __restrict__ kflo) {
  __shared__ alignas(16) u16 sStage[2][64 * 256];  // hi/lo staged K rows (64 KB)
  int bid = blockIdx.x;
  int b = bid >> 4, kb = bid & 15;
  int kbase = kb * 64;
  int nch = vli[32 + b];
  if (kbase >= nch * KT) return;
  int tid = threadIdx.x, wid = tid >> 6, lane = tid & 63;
  int l15 = lane & 15, l16 = lane >> 4;
  int kt = wid & 3, dh = wid >> 2;

  f32x4 zero4 = {0.f, 0.f, 0.f, 0.f};
  f32x4 acc[16];
#pragma unroll
  for (int i = 0; i < 16; ++i) acc[i] = zero4;

  for (int esl = 0; esl < DH; esl += 256) {
    __syncthreads();
    {  // stage K[64 rows][256 e-slice] fp32 -> hi/lo
      int row = tid >> 3;
      int eg = (tid & 7) * 32;
      const float4* src = reinterpret_cast<const float4*>(
          Kg + ((size_t)(b * NKV + kbase + row)) * DH + esl + eg);
      float4 f[8];
#pragma unroll
      for (int i = 0; i < 8; ++i) f[i] = src[i];
      const float* fp = (const float*)&f[0];
#pragma unroll
      for (int g = 0; g < 4; ++g) {
        bf8 vh, vl2;
#pragma unroll
        for (int j = 0; j < 8; ++j) {
          float x = fp[g * 8 + j];
          u16 h = f2bf(x);
          vh[j] = (short)h;
          vl2[j] = (short)f2bf(x - bf2f(h));
        }
        int idx = row * 256 + swz(row, eg + g * 8);
        *(bf8*)(&sStage[0][idx]) = vh;
        *(bf8*)(&sStage[1][idx]) = vl2;
      }
    }
    __syncthreads();
#pragma unroll
    for (int ee = 0; ee < 256; ee += 32) {
      int arow = kt * 16 + l15;
      int aidx = arow * 256 + swz(arow, ee + l16 * 8);
      bf8 ah = *(const bf8*)(&sStage[0][aidx]);
      bf8 al = *(const bf8*)(&sStage[1][aidx]);
#pragma unroll
      for (int dt = 0; dt < 16; ++dt) {
        int drow = dh * 256 + dt * 16 + l15;
        size_t off = (size_t)drow * 512 + esl + ee + l16 * 8;
        bf8 wh = *(const bf8*)(wthi + off);
        bf8 wl = *(const bf8*)(wtlo + off);
        acc[dt] = __builtin_amdgcn_mfma_f32_16x16x32_bf16(ah, wh, acc[dt], 0, 0, 0);
        acc[dt] = __builtin_amdgcn_mfma_f32_16x16x32_bf16(ah, wl, acc[dt], 0, 0, 0);
        acc[dt] = __builtin_amdgcn_mfma_f32_16x16x32_bf16(al, wh, acc[dt], 0, 0, 0);
      }
    }
  }

  // epilogue: via LDS (reuse stage as fp32 [64][256]) -> frag-major hi/lo global
  float* sC = (float*)&sStage[0][0];
  int tglob = b * 64 + (kbase >> 4);
  for (int h = 0; h < 2; ++h) {
    __syncthreads();
    if (dh == h) {
#pragma unroll
      for (int dt = 0; dt < 16; ++dt)
#pragma unroll
        for (int r = 0; r < 4; ++r)
          sC[(kt * 16 + l16 * 4 + r) * 256 + dt * 16 + l15] = acc[dt][r];
    }
    __syncthreads();
    for (int uu = tid; uu < 2048; uu += 512) {
      int l15u = uu & 15, l16u = (uu >> 4) & 3, g8 = (uu >> 6) & 7, ktile = uu >> 9;
      bf8 vh, vl2;
#pragma unroll
      for (int j = 0; j < 8; ++j) {
        float x = sC[(ktile * 16 + l15u) * 256 + g8 * 32 + l16u * 8 + j];
        u16 hh = f2bf(x);
        vh[j] = (short)hh;
        vl2[j] = (short)f2bf(x - bf2f(hh));
      }
      size_t fo = ((size_t)((tglob + ktile) * 16 + h * 8 + g8) * 64 + l16u * 16 + l15u) * 8;
      *(bf8*)(kfhi + fo) = vh;
      *(bf8*)(kflo + fo) = vl2;
    }
  }
}

// V,L -> transposed fragment-major hi/lo (PV B-operand layout):
// idx = b*524288 + ((td*32 + gk)*64 + l16*16 + l15)*8 + j
//   td = d/16, gk = k/32, l16 = (k%32)/8, l15 = d%16, j = k%8
__global__ void convA(const float* __restrict__ Vg, const float* __restrict__ Lg,
                      const int* __restrict__ vli, u16* __restrict__ vthi,
                      u16* __restrict__ vtlo, u16* __restrict__ lthi,
                      u16* __restrict__ ltlo) {
  unsigned u = blockIdx.x * 256 + threadIdx.x;
  int l15 = u & 15, l16 = (u >> 4) & 3, gk = (u >> 6) & 31;
  int td = (u >> 11) & 31, b = (u >> 16) & 31, mat = (int)(u >> 21);
  int nch = vli[32 + b];
  if (gk * 32 >= nch * KT) return;
  const float* src = (mat ? Lg : Vg) +
                     ((size_t)(b * NKV + gk * 32 + l16 * 8)) * DH + td * 16 + l15;
  bf8 vh, vl2;
#pragma unroll
  for (int j = 0; j < 8; ++j) {
    float x = src[(size_t)j * DH];
    u16 h = f2bf(x);
    vh[j] = (short)h;
    vl2[j] = (short)f2bf(x - bf2f(h));
  }
  size_t fo = (size_t)b * 524288 + (size_t)((td * 32 + gk) * 64 + l16 * 16 + l15) * 8;
  if (mat) { *(bf8*)(lthi + fo) = vh; *(bf8*)(ltlo + fo) = vl2; }
  else     { *(bf8*)(vthi + fo) = vh; *(bf8*)(vtlo + fo) = vl2; }
}

// ---------------- fast attention kernel ----------------
__global__ __launch_bounds__(NTHR, 4)
void attn_fast(const float* __restrict__ Qg, const int* __restrict__ vli,
               const u16* __restrict__ kfhi, const u16* __restrict__ kflo,
               const u16* __restrict__ vthi, const u16* __restrict__ vtlo,
               const u16* __restrict__ lthi, const u16* __restrict__ ltlo,
               float* __restrict__ Og) {
  __shared__ alignas(16) u16 sQhi[BQ * DH];  // 32 KB
  __shared__ alignas(16) u16 sQlo[BQ * DH];  // 32 KB
  __shared__ alignas(16) u16 sAhi[BQ * KT];  // 4 KB
  __shared__ alignas(16) u16 sAlo[BQ * KT];
  __shared__ float sM[BQ], sL[BQ], sScale[BQ];
  __shared__ float sPmax[4][BQ], sPsum[4][BQ];

  int bid = blockIdx.x;
  int swb = (bid & 7) * 128 + (bid >> 3);  // XCD swizzle: batch stays on one XCD
  int b = swb >> 5, qt = swb & 31;
  int tid = threadIdx.x;
  int wid = tid >> 6, lane = tid & 63;
  int l15 = lane & 15, l16 = lane >> 4;

  int vl = vli[b];
  bool allm = (vl == 0);
  int nch = vli[32 + b];

  if (tid < BQ) { sM[tid] = -1e30f; sL[tid] = 0.0f; }

  // stage Q tile fp32 -> hi/lo bf16 [32][512] (swizzled)
  {
    int row = tid >> 4;
    int dg = (tid & 15) * 32;
    const float4* src = reinterpret_cast<const float4*>(
        Qg + ((size_t)(b * NQ + qt * BQ + row)) * DH + dg);
    float4 f[8];
#pragma unroll
    for (int i = 0; i < 8; ++i) f[i] = src[i];
    const float* fp = (const float*)&f[0];
#pragma unroll
    for (int g = 0; g < 4; ++g) {
      bf8 vh, vl2;
#pragma unroll
      for (int j = 0; j < 8; ++j) {
        float x = fp[g * 8 + j];
        u16 h = f2bf(x);
        vh[j] = (short)h;
        vl2[j] = (short)f2bf(x - bf2f(h));
      }
      int idx = row * DH + swz(row, dg + g * 8);
      *(bf8*)(&sQhi[idx]) = vh;
      *(bf8*)(&sQlo[idx]) = vl2;
    }
  }
  __syncthreads();

  int mq = wid >> 2, nk = wid & 3;
  f32x4 zero4 = {0.f, 0.f, 0.f, 0.f};
  f32x4 accV[8], accL[8];
#pragma unroll
  for (int i = 0; i < 8; ++i) { accV[i] = zero4; accL[i] = zero4; }

  const float rscale = 0.04419417382415922f;  // 1/sqrt(512)

  for (int kc = 0; kc < nch; ++kc) {
    int kbase = kc * KT;
    int tk = b * 64 + kc * 4 + nk;
    // --- S = Q @ K'^T : A from LDS, B direct from frag-major global (L2)
    f32x4 accS = zero4;
#pragma unroll
    for (int kk = 0; kk < DH; kk += 32) {
      int arow = mq * 16 + l15;
      int aidx = arow * DH + swz(arow, kk + l16 * 8);
      bf8 ah = *(const bf8*)(&sQhi[aidx]);
      bf8 al = *(const bf8*)(&sQlo[aidx]);
      size_t fo = ((size_t)(tk * 16 + (kk >> 5)) * 64 + l16 * 16 + l15) * 8;
      bf8 bh = *(const bf8*)(kfhi + fo);
      bf8 bl = *(const bf8*)(kflo + fo);
      accS = __builtin_amdgcn_mfma_f32_16x16x32_bf16(ah, bh, accS, 0, 0, 0);
      accS = __builtin_amdgcn_mfma_f32_16x16x32_bf16(ah, bl, accS, 0, 0, 0);
      accS = __builtin_amdgcn_mfma_f32_16x16x32_bf16(al, bh, accS, 0, 0, 0);
    }

    // --- online softmax (identical to round-1)
    int colg = kbase + nk * 16 + l15;
    float s[4], mx[4];
#pragma unroll
    for (int r = 0; r < 4; ++r) {
      float x = accS[r] * rscale;
      s[r] = allm ? 0.0f : (colg < vl ? x : MASKV);
      mx[r] = s[r];
    }
#pragma unroll
    for (int off = 1; off < 16; off <<= 1)
#pragma unroll
      for (int r = 0; r < 4; ++r) mx[r] = fmaxf(mx[r], __shfl_xor(mx[r], off));
    if (l15 == 0)
#pragma unroll
      for (int r = 0; r < 4; ++r) sPmax[nk][mq * 16 + l16 * 4 + r] = mx[r];
    __syncthreads();

    float p[4], ps[4];
#pragma unroll
    for (int r = 0; r < 4; ++r) {
      int row = mq * 16 + l16 * 4 + r;
      float mc = fmaxf(fmaxf(sPmax[0][row], sPmax[1][row]),
                       fmaxf(sPmax[2][row], sPmax[3][row]));
      float mn = fmaxf(sM[row], mc);
      p[r] = __expf(s[r] - mn);
      ps[r] = p[r];
    }
#pragma unroll
    for (int off = 1; off < 16; off <<= 1)
#pragma unroll
      for (int r = 0; r < 4; ++r) ps[r] += __shfl_xor(ps[r], off);
    if (l15 == 0)
#pragma unroll
      for (int r = 0; r < 4; ++r) sPsum[nk][mq * 16 + l16 * 4 + r] = ps[r];
#pragma unroll
    for (int r = 0; r < 4; ++r) {
      int row = mq * 16 + l16 * 4 + r;
      int col = nk * 16 + l15;
      u16 h = f2bf(p[r]);
      int idx = row * KT + swz(row, col);
      sAhi[idx] = h;
      sAlo[idx] = f2bf(p[r] - bf2f(h));
    }
    __syncthreads();

    if (nk == 0 && l15 == 0) {
#pragma unroll
      for (int r = 0; r < 4; ++r) {
        int row = mq * 16 + l16 * 4 + r;
        float mc = fmaxf(fmaxf(sPmax[0][row], sPmax[1][row]),
                         fmaxf(sPmax[2][row], sPmax[3][row]));
        float mn = fmaxf(sM[row], mc);
        float sc = __expf(sM[row] - mn);
        sScale[row] = sc;
        sL[row] = sL[row] * sc + (sPsum[0][row] + sPsum[1][row] + sPsum[2][row] + sPsum[3][row]);
        sM[row] = mn;
      }
    }
    __syncthreads();

    float sc4[4];
#pragma unroll
    for (int r = 0; r < 4; ++r) sc4[r] = sScale[mq * 16 + l16 * 4 + r];
#pragma unroll
    for (int i = 0; i < 8; ++i)
#pragma unroll
      for (int r = 0; r < 4; ++r) { accV[i][r] *= sc4[r]; accL[i][r] *= sc4[r]; }

    // --- PV: A from sA (LDS), B = Vt/Lt frag-major global (L2)
    bf8 pah[2], pal[2];
#pragma unroll
    for (int ks = 0; ks < 2; ++ks) {
      int arow = mq * 16 + l15;
      int aidx = arow * KT + swz(arow, ks * 32 + l16 * 8);
      pah[ks] = *(const bf8*)(&sAhi[aidx]);
      pal[ks] = *(const bf8*)(&sAlo[aidx]);
    }
#pragma unroll
    for (int i = 0; i < 8; ++i) {
      int dt = nk + i * 4;
      f32x4 a0 = accV[i], a1 = accL[i];
#pragma unroll
      for (int ks = 0; ks < 2; ++ks) {
        size_t fo = (size_t)b * 524288 +
                    (size_t)((dt * 32 + (kc * 2 + ks)) * 64 + l16 * 16 + l15) * 8;
        bf8 bh = *(const bf8*)(vthi + fo);
        bf8 bl = *(const bf8*)(vtlo + fo);
        a0 = __builtin_amdgcn_mfma_f32_16x16x32_bf16(pah[ks], bh, a0, 0, 0, 0);
        a0 = __builtin_amdgcn_mfma_f32_16x16x32_bf16(pah[ks], bl, a0, 0, 0, 0);
        a0 = __builtin_amdgcn_mfma_f32_16x16x32_bf16(pal[ks], bh, a0, 0, 0, 0);
        bf8 ch = *(const bf8*)(lthi + fo);
        bf8 cl = *(const bf8*)(ltlo + fo);
        a1 = __builtin_amdgcn_mfma_f32_16x16x32_bf16(pah[ks], ch, a1, 0, 0, 0);
        a1 = __builtin_amdgcn_mfma_f32_16x16x32_bf16(pah[ks], cl, a1, 0, 0, 0);
        a1 = __builtin_amdgcn_mfma_f32_16x16x32_bf16(pal[ks], ch, a1, 0, 0, 0);
      }
      accV[i] = a0;
      accL[i] = a1;
    }
  }

  // epilogue
  float linv[4];
#pragma unroll
  for (int r = 0; r < 4; ++r) linv[r] = 1.0f / sL[mq * 16 + l16 * 4 + r];
  float* outV = Og;
  float* outL = Og + (size_t)NB * NQ * DH;
#pragma unroll
  for (int i = 0; i < 8; ++i) {
    int dt = nk + i * 4;
    int d = dt * 16 + l15;
#pragma unroll
    for (int r = 0; r < 4; ++r) {
      int q = qt * BQ + mq * 16 + l16 * 4 + r;
      size_t off = ((size_t)(b * NQ + q)) * DH + d;
      outV[off] = accV[i][r] * linv[r];
      outL[off] = accL[i][r] * linv[r];
    }
  }
}

// ---------------- fallback path (round-1, known-correct) ----------------

__global__ void prep_w(const float* __restrict__ W, u16* __restrict__ whi,
                       u16* __restrict__ wlo) {
  int i = (blockIdx.x * 256 + threadIdx.x) * 4;
  float4 f = *reinterpret_cast<const float4*>(W + i);
  const float* fp = (const float*)&f;
#pragma unroll
  for (int j = 0; j < 4; ++j) {
    float x = fp[j];
    u16 h = f2bf(x);
    whi[i + j] = h;
    wlo[i + j] = f2bf(x - bf2f(h));
  }
}

__global__ __launch_bounds__(NTHR)
void attn_fb(const float* __restrict__ Qg, const float* __restrict__ Kg,
             const float* __restrict__ Vg, const float* __restrict__ Lg,
             const int* __restrict__ vlraw, const u16* __restrict__ Whi,
             const u16* __restrict__ Wlo, float* __restrict__ Og) {
  __shared__ u16 sPhi[BQ * DH];
  __shared__ u16 sPlo[BQ * DH];
  __shared__ u16 sSthi[16384];
  __shared__ u16 sStlo[16384];
  __shared__ u16 sAhi[BQ * KT];
  __shared__ u16 sAlo[BQ * KT];
  __shared__ float sM[BQ], sL[BQ], sScale[BQ];
  __shared__ float sPmax[4][BQ], sPsum[4][BQ];

  int bid = blockIdx.x;
  int swb = (bid & 7) * 128 + (bid >> 3);
  int b = swb >> 5, qt = swb & 31;
  int tid = threadIdx.x;
  int wid = tid >> 6, lane = tid & 63;
  int l15 = lane & 15, l16 = lane >> 4;

  bool is64 = true;
  for (int j = 1; j < 32; j += 2) is64 = is64 && (vlraw[j] == 0);
  int vl = is64 ? vlraw[2 * b] : vlraw[b];
  bool allm = (vl == 0);
  int vleff = allm ? NKV : vl;
  int nch = (vleff + KT - 1) / KT;

  if (tid < BQ) { sM[tid] = -1e30f; sL[tid] = 0.0f; }

  {
    int row = tid >> 4;
    int dg = (tid & 15) * 32;
    const float4* src = reinterpret_cast<const float4*>(
        Qg + ((size_t)(b * NQ + qt * BQ + row)) * DH + dg);
    float4 f[8];
#pragma unroll
    for (int i = 0; i < 8; ++i) f[i] = src[i];
    const float* fp = (const float*)&f[0];
#pragma unroll
    for (int g = 0; g < 4; ++g) {
      bf8 vh, vlo2;
#pragma unroll
      for (int j = 0; j < 8; ++j) {
        float x = fp[g * 8 + j];
        u16 h = f2bf(x);
        vh[j] = (short)h;
        vlo2[j] = (short)f2bf(x - bf2f(h));
      }
      int idx = row * DH + swz(row, dg + g * 8);
      *(bf8*)(&sSthi[idx]) = vh;
      *(bf8*)(&sStlo[idx]) = vlo2;
    }
  }
  __syncthreads();

  f32x4 zero4 = {0.f, 0.f, 0.f, 0.f};
  f32x4 accP[2][4];
#pragma unroll
  for (int mi = 0; mi < 2; ++mi)
#pragma unroll
    for (int es = 0; es < 4; ++es) accP[mi][es] = zero4;

  for (int kk = 0; kk < DH; kk += 32) {
    bf8 qh[2], ql[2];
#pragma unroll
    for (int mi = 0; mi < 2; ++mi) {
      int row = mi * 16 + l15;
      int idx = row * DH + swz(row, kk + l16 * 8);
      qh[mi] = *(const bf8*)(&sSthi[idx]);
      ql[mi] = *(const bf8*)(&sStlo[idx]);
    }
#pragma unroll
    for (int es = 0; es < 4; ++es) {
      int e = wid * 64 + es * 16 + l15;
      int off = e * DH + kk + l16 * 8;
      bf8 wh = *(const bf8*)(Whi + off);
      bf8 wl = *(const bf8*)(Wlo + off);
#pragma unroll
      for (int mi = 0; mi < 2; ++mi) {
        accP[mi][es] = __builtin_amdgcn_mfma_f32_16x16x32_bf16(qh[mi], wh, accP[mi][es], 0, 0, 0);
        accP[mi][es] = __builtin_amdgcn_mfma_f32_16x16x32_bf16(qh[mi], wl, accP[mi][es], 0, 0, 0);
        accP[mi][es] = __builtin_amdgcn_mfma_f32_16x16x32_bf16(ql[mi], wh, accP[mi][es], 0, 0, 0);
      }
    }
  }
#pragma unroll
  for (int mi = 0; mi < 2; ++mi)
#pragma unroll
    for (int es = 0; es < 4; ++es)
#pragma unroll
      for (int r = 0; r < 4; ++r) {
        int row = mi * 16 + l16 * 4 + r;
        int col = wid * 64 + es * 16 + l15;
        float x = accP[mi][es][r];
        u16 h = f2bf(x);
        int idx = row * DH + swz(row, col);
        sPhi[idx] = h;
        sPlo[idx] = f2bf(x - bf2f(h));
      }
  __syncthreads();

  int mq = wid >> 2, nk = wid & 3;
  f32x4 accV[8], accL[8];
#pragma unroll
  for (int i = 0; i < 8; ++i) { accV[i] = zero4; accL[i] = zero4; }

  const float rscale = 0.04419417382415922f;

  for (int kc = 0; kc < nch; ++kc) {
    int kbase = kc * KT;
    f32x4 accS = zero4;
#pragma unroll
    for (int dsl = 0; dsl < DH; dsl += 256) {
      __syncthreads();
      {
        int row = tid >> 3;
        int dg = (tid & 7) * 32;
        const float4* src = reinterpret_cast<const float4*>(
            Kg + ((size_t)(b * NKV + kbase + row)) * DH + dsl + dg);
        float4 f[8];
#pragma unroll
        for (int i = 0; i < 8; ++i) f[i] = src[i];
        const float* fp = (const float*)&f[0];
#pragma unroll
        for (int g = 0; g < 4; ++g) {
          bf8 vh, vlo2;
#pragma unroll
          for (int j = 0; j < 8; ++j) {
            float x = fp[g * 8 + j];
            u16 h = f2bf(x);
            vh[j] = (short)h;
            vlo2[j] = (short)f2bf(x - bf2f(h));
          }
          int idx = row * 256 + swz(row, dg + g * 8);
          *(bf8*)(&sSthi[idx]) = vh;
          *(bf8*)(&sStlo[idx]) = vlo2;
        }
      }
      __syncthreads();
#pragma unroll
      for (int kk = 0; kk < 256; kk += 32) {
        int arow = mq * 16 + l15;
        int aidx = arow * DH + swz(arow, dsl + kk + l16 * 8);
        bf8 ah = *(const bf8*)(&sPhi[aidx]);
        bf8 al = *(const bf8*)(&sPlo[aidx]);
        int brow = nk * 16 + l15;
        int bidx = brow * 256 + swz(brow, kk + l16 * 8);
        bf8 bh = *(const bf8*)(&sSthi[bidx]);
        bf8 bl = *(const bf8*)(&sStlo[bidx]);
        accS = __builtin_amdgcn_mfma_f32_16x16x32_bf16(ah, bh, accS, 0, 0, 0);
        accS = __builtin_amdgcn_mfma_f32_16x16x32_bf16(ah, bl, accS, 0, 0, 0);
        accS = __builtin_amdgcn_mfma_f32_16x16x32_bf16(al, bh, accS, 0, 0, 0);
      }
    }

    int colg = kbase + nk * 16 + l15;
    float s[4], mx[4];
#pragma unroll
    for (int r = 0; r < 4; ++r) {
      float x = accS[r] * rscale;
      s[r] = allm ? 0.0f : (colg < vl ? x : MASKV);
      mx[r] = s[r];
    }
#pragma unroll
    for (int off = 1; off < 16; off <<= 1)
#pragma unroll
      for (int r = 0; r < 4; ++r) mx[r] = fmaxf(mx[r], __shfl_xor(mx[r], off));
    if (l15 == 0)
#pragma unroll
      for (int r = 0; r < 4; ++r) sPmax[nk][mq * 16 + l16 * 4 + r] = mx[r];
    __syncthreads();

    float p[4], ps[4];
#pragma unroll
    for (int r = 0; r < 4; ++r) {
      int row = mq * 16 + l16 * 4 + r;
      float mc = fmaxf(fmaxf(sPmax[0][row], sPmax[1][row]),
                       fmaxf(sPmax[2][row], sPmax[3][row]));
      float mn = fmaxf(sM[row], mc);
      p[r] = __expf(s[r] - mn);
      ps[r] = p[r];
    }
#pragma unroll
    for (int off = 1; off < 16; off <<= 1)
#pragma unroll
      for (int r = 0; r < 4; ++r) ps[r] += __shfl_xor(ps[r], off);
    if (l15 == 0)
#pragma unroll
      for (int r = 0; r < 4; ++r) sPsum[nk][mq * 16 + l16 * 4 + r] = ps[r];
#pragma unroll
    for (int r = 0; r < 4; ++r) {
      int row = mq * 16 + l16 * 4 + r;
      int col = nk * 16 + l15;
      u16 h = f2bf(p[r]);
      int idx = row * KT + swz(row, col);
      sAhi[idx] = h;
      sAlo[idx] = f2bf(p[r] - bf2f(h));
    }
    __syncthreads();

    if (nk == 0 && l15 == 0) {
#pragma unroll
      for (int r = 0; r < 4; ++r) {
        int row = mq * 16 + l16 * 4 + r;
        float mc = fmaxf(fmaxf(sPmax[0][row], sPmax[1][row]),
                         fmaxf(sPmax[2][row], sPmax[3][row]));
        float mn = fmaxf(sM[row], mc);
        float sc = __expf(sM[row] - mn);
        sScale[row] = sc;
        sL[row] = sL[row] * sc + (sPsum[0][row] + sPsum[1][row] + sPsum[2][row] + sPsum[3][row]);
        sM[row] = mn;
      }
    }
    __syncthreads();

    float sc4[4];
#pragma unroll
    for (int r = 0; r < 4; ++r) sc4[r] = sScale[mq * 16 + l16 * 4 + r];
#pragma unroll
    for (int i = 0; i < 8; ++i)
#pragma unroll
      for (int r = 0; r < 4; ++r) { accV[i][r] *= sc4[r]; accL[i][r] *= sc4[r]; }

#pragma unroll
    for (int mat = 0; mat < 2; ++mat) {
      const float* src0 = (mat == 0) ? Vg : Lg;
#pragma unroll
      for (int dsl = 0; dsl < DH; dsl += 256) {
        __syncthreads();
        {
          int n = tid & 63;
          int dg = (tid >> 6) * 32;
          const float4* s4 = reinterpret_cast<const float4*>(
              src0 + ((size_t)(b * NKV + kbase + n)) * DH + dsl + dg);
          float4 f[8];
#pragma unroll
          for (int i = 0; i < 8; ++i) f[i] = s4[i];
          const float* fp = (const float*)&f[0];
#pragma unroll
          for (int j = 0; j < 32; ++j) {
            float x = fp[j];
            u16 h = f2bf(x);
            int d = dg + j;
            int idx = d * 64 + swz(d, n);
            sSthi[idx] = h;
            sStlo[idx] = f2bf(x - bf2f(h));
          }
        }
        __syncthreads();
        bf8 ah[2], al[2];
#pragma unroll
        for (int ks = 0; ks < 2; ++ks) {
          int arow = mq * 16 + l15;
          int aidx = arow * KT + swz(arow, ks * 32 + l16 * 8);
          ah[ks] = *(const bf8*)(&sAhi[aidx]);
          al[ks] = *(const bf8*)(&sAlo[aidx]);
        }
#pragma unroll
        for (int d4 = 0; d4 < 4; ++d4) {
          int dsub = (wid & 3) + d4 * 4;
          int ai = (dsl >> 8) * 4 + d4;
          f32x4 acc = (mat == 0) ? accV[ai] : accL[ai];
#pragma unroll
          for (int ks = 0; ks < 2; ++ks) {
            int brow = dsub * 16 + l15;
            int bidx = brow * 64 + swz(brow, ks * 32 + l16 * 8);
            bf8 bh = *(const bf8*)(&sSthi[bidx]);
            bf8 bl = *(const bf8*)(&sStlo[bidx]);
            acc = __builtin_amdgcn_mfma_f32_16x16x32_bf16(ah[ks], bh, acc, 0, 0, 0);
            acc = __builtin_amdgcn_mfma_f32_16x16x32_bf16(ah[ks], bl, acc, 0, 0, 0);
            acc = __builtin_amdgcn_mfma_f32_16x16x32_bf16(al[ks], bh, acc, 0, 0, 0);
          }
          if (mat == 0) accV[ai] = acc; else accL[ai] = acc;
        }
      }
    }
  }

  float linv[4];
#pragma unroll
  for (int r = 0; r < 4; ++r) linv[r] = 1.0f / sL[mq * 16 + l16 * 4 + r];
  float* outV = Og;
  float* outL = Og + (size_t)NB * NQ * DH;
#pragma unroll
  for (int sl = 0; sl < 2; ++sl)
#pragma unroll
    for (int d4 = 0; d4 < 4; ++d4) {
      int ai = sl * 4 + d4;
      int d = sl * 256 + ((wid & 3) + d4 * 4) * 16 + l15;
#pragma unroll
      for (int r = 0; r < 4; ++r) {
        int q = qt * BQ + mq * 16 + l16 * 4 + r;
        size_t off = ((size_t)(b * NQ + q)) * DH + d;
        outV[off] = accV[ai][r] * linv[r];
        outL[off] = accL[ai][r] * linv[r];
      }
    }
}

extern "C" void kernel_launch(void* const* d_in, const int* in_sizes, int n_in,
                              void* d_out, int out_size, void* d_ws, size_t ws_size,
                              hipStream_t stream) {
  (void)in_sizes; (void)n_in; (void)out_size;
  const float* Qg = (const float*)d_in[0];
  const float* Kg = (const float*)d_in[1];
  const float* Vg = (const float*)d_in[2];
  const float* Lg = (const float*)d_in[3];
  const float* W  = (const float*)d_in[4];
  const int* vlr  = (const int*)d_in[5];
  float* Og = (float*)d_out;
  char* ws = (char*)d_ws;

  if (ws_size >= WS_NEED) {
    int* vli  = (int*)(ws + O_VLI);
    u16* wthi = (u16*)(ws + O_WTHI);
    u16* wtlo = (u16*)(ws + O_WTLO);
    u16* kfhi = (u16*)(ws + O_KFHI);
    u16* kflo = (u16*)(ws + O_KFLO);
    u16* vthi = (u16*)(ws + O_VTHI);
    u16* vtlo = (u16*)(ws + O_VTLO);
    u16* lthi = (u16*)(ws + O_LTHI);
    u16* ltlo = (u16*)(ws + O_LTLO);
    prep_fast<<<dim3(1024), dim3(256), 0, stream>>>(W, vlr, wthi, wtlo, vli);
    projk<<<dim3(512), dim3(512), 0, stream>>>(Kg, wthi, wtlo, vli, kfhi, kflo);
    convA<<<dim3(16384), dim3(256), 0, stream>>>(Vg, Lg, vli, vthi, vtlo, lthi, ltlo);
    attn_fast<<<dim3(1024), dim3(NTHR), 0, stream>>>(Qg, vli, kfhi, kflo, vthi, vtlo,
                                                     lthi, ltlo, Og);
  } else {
    u16* whi = (u16*)d_ws;
    u16* wlo = whi + 512 * 512;
    prep_w<<<dim3(256), dim3(256), 0, stream>>>(W, whi, wlo);
    attn_fb<<<dim3(1024), dim3(NTHR), 0, stream>>>(Qg, Kg, Vg, Lg, vlr, whi, wlo, Og);
  }
}